// Round 4
// baseline (291.790 us; speedup 1.0000x reference)
//
#include <hip/hip_runtime.h>

// FCOS post-processing: scores = sqrt(sig(cls)*sig(cent)); top-100 of 21M;
// gather (faithful flat[pt_idx] quirk); box decode; greedy NMS (K=100, IoU>0.5).
//
// ws layout: [0..15] header {cand_count, rescan_flag, T_bin, arrival}
//            [16..4111] hist[1024] (fast scores in [0.80,1.0), width 1/5120)
//            [4352 ...] cand_score[cap] ; cand_idx[cap]
//
// Selection strategy: scan collects candidates with FAST math (self-consistent
// binning); finalize recomputes PRECISE scores (bit-identical to reference)
// for the ~150 survivors and does exact top-k + NMS. 1-bin margin covers the
// fast-vs-precise epsilon (~1e-6 << bin width 1.95e-4).

#define NPTS 262144
#define NCLS 80
#define NFLAT (NPTS * NCLS)      // 20,971,520
#define NF4 (NFLAT / 4)          // 5,242,880
#define KDET 100
#define HB 1024
#define HIST_LO 0.80f
#define HIST_SCALE 5120.0f       // HB / 0.2
#define BINW (1.0f / HIST_SCALE)
#define THETA0 0.94f             // candidate floor (analytic top-100 cut ~0.953)
#define W_CAND (1.0f / (THETA0 * THETA0))   // w = (1+e^-a)(1+e^-b) <= this
#define W_HIST (1.0f / (HIST_LO * HIST_LO)) // = 1.5625
#define MCAP 1024
#define SBUF 512
#define NB1 2560                 // NB1*NT1*UB == NF4 exactly
#define NT1 256
#define UB 8
#define TT (NB1 * NT1)           // 655,360 threads

// fast sigmoid/score: used ONLY for candidate collection + binning
__device__ __forceinline__ float s_from_w(float w) {
    return sqrtf(__builtin_amdgcn_rcpf(w));
}
// precise score pieces (bit-identical to reference / round-1 absmax=0 path)
__device__ __forceinline__ float sigm_p(float x) {
    return 1.0f / (1.0f + expf(-x));
}
__device__ __forceinline__ int bin_of(float s) {
    int b = (int)((s - HIST_LO) * HIST_SCALE);
    return b < 0 ? 0 : (b > HB - 1 ? HB - 1 : b);
}

// ------ Pass 1: w-space scan -> histogram + candidates; last block picks T ----
__global__ __launch_bounds__(NT1) void k_score_hist(
    const float* __restrict__ cls, const float* __restrict__ cent,
    unsigned* __restrict__ hist, unsigned* __restrict__ hdr,
    float* __restrict__ cscore, unsigned* __restrict__ cidx, int cap)
{
    __shared__ unsigned sh[HB];
    __shared__ float    sbs[SBUF];
    __shared__ unsigned sbi[SBUF];
    __shared__ unsigned sbn, sbase, sbm;
    __shared__ int      lastblk;
    for (int i = threadIdx.x; i < HB; i += NT1) sh[i] = 0;
    if (threadIdx.x == 0) sbn = 0;
    __syncthreads();

    const float4* c4 = (const float4*)cls;
    int tid = blockIdx.x * NT1 + threadIdx.x;

    // 8 independent float4 loads + 8 cent loads in flight (deep MLP)
    float4 v[UB];
    float  cb[UB];
    #pragma unroll
    for (int u = 0; u < UB; ++u) v[u] = c4[tid + u * TT];
    #pragma unroll
    for (int u = 0; u < UB; ++u) cb[u] = cent[(tid + u * TT) / 20];

    #pragma unroll
    for (int u = 0; u < UB; ++u) {
        int g = tid + u * TT;
        float f = 1.0f + __expf(-cb[u]);      // (1+e^-b)
        float sv[4] = {v[u].x, v[u].y, v[u].z, v[u].w};
        #pragma unroll
        for (int i = 0; i < 4; ++i) {
            float w = (1.0f + __expf(-sv[i])) * f;
            if (w <= W_HIST) {                // fast-s >= ~0.80 (~2% of elems)
                float s = s_from_w(w);
                atomicAdd(&sh[bin_of(s)], 1u);
                if (w <= W_CAND) {            // fast-s >= ~0.94 (~600 total)
                    unsigned pos = atomicAdd(&sbn, 1u);
                    if (pos < SBUF) { sbs[pos] = s; sbi[pos] = (unsigned)(g * 4 + i); }
                    else {
                        unsigned q = atomicAdd(&hdr[0], 1u);
                        if (q < (unsigned)cap) { cscore[q] = s; cidx[q] = (unsigned)(g * 4 + i); }
                    }
                }
            }
        }
    }
    __syncthreads();
    // merge histogram (skip zero bins) + flush staging (1 counter atomic/block)
    for (int i = threadIdx.x; i < HB; i += NT1) {
        unsigned c = sh[i];
        if (c) atomicAdd(&hist[i], c);
    }
    if (threadIdx.x == 0) {
        unsigned m = sbn < SBUF ? sbn : SBUF;
        sbm = m;
        sbase = m ? atomicAdd(&hdr[0], m) : 0u;
    }
    __syncthreads();
    for (unsigned i = threadIdx.x; i < sbm; i += NT1) {
        unsigned q = sbase + i;
        if (q < (unsigned)cap) { cscore[q] = sbs[i]; cidx[q] = sbi[i]; }
    }
    __syncthreads();
    if (threadIdx.x == 0) {
        __threadfence();
        lastblk = (atomicAdd(&hdr[3], 1u) == (unsigned)(gridDim.x - 1));
    }
    __syncthreads();
    if (!lastblk) return;
    __threadfence();
    for (int i = threadIdx.x; i < HB; i += NT1)
        sh[i] = __hip_atomic_load(&hist[i], __ATOMIC_RELAXED, __HIP_MEMORY_SCOPE_AGENT);
    __syncthreads();
    if (threadIdx.x == 0) {
        unsigned cum = 0; int T = -1;
        for (int b = HB - 1; b >= 0; --b) { cum += sh[b]; if (cum >= KDET) { T = b; break; } }
        unsigned cand = __hip_atomic_load(&hdr[0], __ATOMIC_RELAXED, __HIP_MEMORY_SCOPE_AGENT);
        int rescan;
        if (T < 0) { T = 0; rescan = 1; }              // <100 fast-s >= 0.80 (never here)
        else {
            // finalize filters bins >= T-1; candidates must cover that + eps
            float edgeTm1 = HIST_LO + (float)(T - 1) * BINW;
            rescan = (edgeTm1 < THETA0 + 2.0f * BINW) || (cand > (unsigned)cap);
        }
        ((int*)hdr)[2] = T;
        if (rescan) hdr[0] = 0;                        // reset for k_rescan
        __threadfence();
        hdr[1] = (unsigned)rescan;
    }
}

// ------ Pass 2 (fallback, early-exit): collect all with bin >= T-1 ------------
__global__ __launch_bounds__(NT1) void k_rescan(
    const float* __restrict__ cls, const float* __restrict__ cent,
    unsigned* __restrict__ hdr, float* __restrict__ cscore,
    unsigned* __restrict__ cidx, int cap)
{
    if (hdr[1] == 0) return;
    int T = ((const int*)hdr)[2];
    int Tm = T > 0 ? T - 1 : 0;
    const float4* c4 = (const float4*)cls;
    int tid = blockIdx.x * NT1 + threadIdx.x;
    float4 v[UB];
    float  cb[UB];
    #pragma unroll
    for (int u = 0; u < UB; ++u) v[u] = c4[tid + u * TT];
    #pragma unroll
    for (int u = 0; u < UB; ++u) cb[u] = cent[(tid + u * TT) / 20];
    #pragma unroll
    for (int u = 0; u < UB; ++u) {
        int g = tid + u * TT;
        float f = 1.0f + __expf(-cb[u]);
        float sv[4] = {v[u].x, v[u].y, v[u].z, v[u].w};
        #pragma unroll
        for (int i = 0; i < 4; ++i) {
            float w = (1.0f + __expf(-sv[i])) * f;
            if (w <= W_HIST) {
                float s = s_from_w(w);
                if (bin_of(s) >= Tm) {
                    unsigned pos = atomicAdd(&hdr[0], 1u);
                    if (pos < (unsigned)cap) { cscore[pos] = s; cidx[pos] = (unsigned)(g * 4 + i); }
                }
            }
        }
    }
}

// ------ Pass 3: precise top-100, gather/decode, stable sort, NMS, outputs -----
__global__ __launch_bounds__(256) void k_finalize(
    const float* __restrict__ cls, const float* __restrict__ cent,
    const float* __restrict__ boxp, const float* __restrict__ pts,
    const float* __restrict__ strd,
    const unsigned* __restrict__ hdr, const float* __restrict__ cscore,
    const unsigned* __restrict__ cidx, int cap, float* __restrict__ out)
{
    __shared__ float    ss[MCAP];
    __shared__ unsigned si[MCAP];
    __shared__ float    ps[MCAP];        // precise scores
    __shared__ unsigned mcnt;
    __shared__ float    tks[KDET];       // top-100, lax.top_k order
    __shared__ unsigned tkj[KDET];
    __shared__ float sel_s[KDET];
    __shared__ int   sel_c[KDET];
    __shared__ float sel_b[KDET][4];
    __shared__ int   ordv[KDET];
    __shared__ float bs[KDET][4];
    __shared__ float sso[KDET];
    __shared__ int   cso[KDET];
    __shared__ unsigned char keepA[KDET];
    __shared__ float ioum[KDET * KDET];

    int T = ((const int*)hdr)[2];
    int Tm = T > 0 ? T - 1 : 0;
    unsigned n = hdr[0]; if (n > (unsigned)cap) n = (unsigned)cap;
    if (threadIdx.x == 0) mcnt = 0;
    __syncthreads();

    // filter candidates to bin >= T-1 (expected ~120-250)
    for (unsigned i = threadIdx.x; i < n; i += 256) {
        float s = cscore[i];
        if (bin_of(s) >= Tm) {
            unsigned p = atomicAdd(&mcnt, 1u);
            if (p < MCAP) { ss[p] = s; si[p] = cidx[i]; }
        }
    }
    __syncthreads();
    unsigned M = mcnt < MCAP ? mcnt : MCAP;

    // precise score for each candidate (bit-identical to reference formula)
    for (unsigned m = threadIdx.x; m < M; m += 256) {
        unsigned j = si[m];
        ps[m] = sqrtf(sigm_p(cls[j]) * sigm_p(cent[j / (unsigned)NCLS]));
    }
    if (threadIdx.x < KDET) { tks[threadIdx.x] = -1.0f; tkj[threadIdx.x] = 0u; }
    __syncthreads();

    // exact top-100 by (precise score desc, idx asc) via rank counting
    for (unsigned m = threadIdx.x; m < M; m += 256) {
        float sm = ps[m]; unsigned jm = si[m];
        int rank = 0;
        for (unsigned q = 0; q < M; ++q) {
            float sq = ps[q]; unsigned jq = si[q];
            if (sq > sm || (sq == sm && jq < jm)) ++rank;
        }
        if (rank < KDET) { tks[rank] = sm; tkj[rank] = jm; }
    }
    __syncthreads();

    // gather + decode (faithful quirk: score gathered at flat[pt_idx])
    if (threadIdx.x < KDET) {
        int k = threadIdx.x;
        unsigned j = tkj[k];
        unsigned pt = j / (unsigned)NCLS;
        sel_c[k] = (int)(j % (unsigned)NCLS);
        sel_s[k] = sqrtf(sigm_p(cls[pt]) * sigm_p(cent[pt / (unsigned)NCLS]));
        float l = boxp[pt * 4 + 0], tt = boxp[pt * 4 + 1];
        float r = boxp[pt * 4 + 2], bb = boxp[pt * 4 + 3];
        float st = strd[pt];
        float px = pts[pt * 2 + 0], py = pts[pt * 2 + 1];
        sel_b[k][0] = __fsub_rn(px, __fmul_rn(l,  st));
        sel_b[k][1] = __fsub_rn(py, __fmul_rn(tt, st));
        sel_b[k][2] = __fadd_rn(px, __fmul_rn(r,  st));
        sel_b[k][3] = __fadd_rn(py, __fmul_rn(bb, st));
    }
    __syncthreads();

    // stable argsort(-sel_s): ties -> lower k (jnp.argsort stable)
    if (threadIdx.x < KDET) {
        int k = threadIdx.x; float sk = sel_s[k]; int rank = 0;
        for (int j = 0; j < KDET; ++j) {
            float sj = sel_s[j];
            if (sj > sk || (sj == sk && j < k)) ++rank;
        }
        ordv[rank] = k;
    }
    __syncthreads();
    if (threadIdx.x < KDET) {
        int i = threadIdx.x, o = ordv[i];
        sso[i] = sel_s[o]; cso[i] = sel_c[o];
        bs[i][0] = sel_b[o][0]; bs[i][1] = sel_b[o][1];
        bs[i][2] = sel_b[o][2]; bs[i][3] = sel_b[o][3];
        keepA[i] = 1;
    }
    __syncthreads();

    // pairwise IoU (exact reference formula), 10000/256 iters
    for (int t = threadIdx.x; t < KDET * KDET; t += 256) {
        int i = t / KDET, j = t % KDET;
        float ax1 = bs[i][0], ay1 = bs[i][1], ax2 = bs[i][2], ay2 = bs[i][3];
        float bx1 = bs[j][0], by1 = bs[j][1], bx2 = bs[j][2], by2 = bs[j][3];
        float areaA = (ax2 - ax1) * (ay2 - ay1);
        float areaB = (bx2 - bx1) * (by2 - by1);
        float lx = fmaxf(ax1, bx1), ly = fmaxf(ay1, by1);
        float rx = fminf(ax2, bx2), ry = fminf(ay2, by2);
        float w = fmaxf(rx - lx, 0.0f), h = fmaxf(ry - ly, 0.0f);
        float inter = w * h;
        ioum[t] = inter / (areaA + areaB - inter + 1e-9f);
    }
    __syncthreads();

    // greedy NMS on wave 0 only: keep flags in lane registers, zero barriers
    if (threadIdx.x < 64) {
        int L = threadIdx.x;
        int k0 = 1, k1 = 1;                  // boxes L and L+64
        #pragma unroll 1
        for (int i = 0; i < KDET; ++i) {
            int owner = (i < 64) ? i : (i - 64);
            int flag  = (i < 64) ? k0 : k1;
            int keep_i = __shfl(flag, owner, 64);
            if (keep_i) {
                if (L > i && ioum[i * KDET + L] > 0.5f) k0 = 0;
                int j2 = L + 64;
                if (j2 > i && j2 < KDET && ioum[i * KDET + j2] > 0.5f) k1 = 0;
            }
        }
        keepA[L] = (unsigned char)k0;
        if (L + 64 < KDET) keepA[L + 64] = (unsigned char)k1;
    }
    __syncthreads();

    // outputs: boxes [100,4] | scores [100] | classes [100] (float, -1 suppressed)
    if (threadIdx.x < KDET) {
        int i = threadIdx.x;
        bool kp = keepA[i] != 0;
        out[i * 4 + 0] = kp ? bs[i][0] : 0.0f;
        out[i * 4 + 1] = kp ? bs[i][1] : 0.0f;
        out[i * 4 + 2] = kp ? bs[i][2] : 0.0f;
        out[i * 4 + 3] = kp ? bs[i][3] : 0.0f;
        out[4 * KDET + i] = kp ? sso[i] : 0.0f;
        out[5 * KDET + i] = kp ? (float)cso[i] : -1.0f;
    }
}

extern "C" void kernel_launch(void* const* d_in, const int* in_sizes, int n_in,
                              void* d_out, int out_size, void* d_ws, size_t ws_size,
                              hipStream_t stream)
{
    const float* cls  = (const float*)d_in[0];
    const float* boxp = (const float*)d_in[1];
    const float* cent = (const float*)d_in[2];
    const float* pts  = (const float*)d_in[3];
    const float* strd = (const float*)d_in[4];
    float* out = (float*)d_out;

    char* ws = (char*)d_ws;
    unsigned* hdr  = (unsigned*)ws;
    unsigned* hist = (unsigned*)(ws + 16);
    size_t capS = ws_size > 4360 ? (ws_size - 4352) / 8 : 64;
    int cap = (int)(capS > 32768 ? 32768 : capS);
    float*    cscore = (float*)(ws + 4352);
    unsigned* cidx   = (unsigned*)(ws + 4352 + (size_t)cap * 4);

    hipMemsetAsync(d_ws, 0, 4112, stream);  // header + hist
    hipLaunchKernelGGL(k_score_hist, dim3(NB1), dim3(NT1), 0, stream,
                       cls, cent, hist, hdr, cscore, cidx, cap);
    hipLaunchKernelGGL(k_rescan, dim3(NB1), dim3(NT1), 0, stream,
                       cls, cent, hdr, cscore, cidx, cap);
    hipLaunchKernelGGL(k_finalize, dim3(1), dim3(256), 0, stream,
                       cls, cent, boxp, pts, strd, hdr, cscore, cidx, cap, out);
}

// Round 9
// 285.164 us; speedup vs baseline: 1.0232x; 1.0232x over previous
//
#include <hip/hip_runtime.h>

// FCOS post-processing: scores = sqrt(sig(cls)*sig(cent)); top-100 of 21M;
// gather (faithful flat[pt_idx] quirk); box decode; greedy NMS (K=100, IoU>0.5).
//
// Scan: register-batched loads (8x float4 + 8x cent per thread) pinned by an
// asm memory fence so the compiler CANNOT sink loads into the consume loop
// (round-4 failure: VGPR=12/32, 2 loads in flight, 277 GB/s latency-bound).
// Fast w-space test: s>=theta  <=>  (1+e^-a)(1+e^-b) <= 1/theta^2.
// Histogram over fast-s in [0.90,1) -> exact threshold bin T; finalize
// recomputes PRECISE scores for ~150 survivors (bins >= T-1), exact top-100,
// decode, stable argsort, wave-register NMS. Validated structure (round 4:
// passed, absmax=0).
//
// ws: [0..15] hdr {cand_count, rescan_flag, T_bin, arrival}
//     [16..1039] hist[256] (fast s in [0.90,1.0), width 1/2560)
//     [2048...] cand_score[cap] ; cand_idx[cap]

#define NPTS 262144
#define NCLS 80
#define NFLAT (NPTS * NCLS)      // 20,971,520
#define NF4 (NFLAT / 4)          // 5,242,880
#define KDET 100
#define HB 256
#define HIST_LO 0.90f
#define HIST_SCALE 2560.0f       // HB / 0.1
#define BINW (1.0f / HIST_SCALE)
#define THETA0 0.94f             // candidate floor (analytic top-100 cut ~0.953)
#define W_CAND (1.0f / (THETA0 * THETA0))
#define W_HIST (1.0f / (HIST_LO * HIST_LO))
#define MCAP 1024
#define SBUF 128
#define NB1 2560                 // NB1*NT1*UB == NF4 exactly
#define NT1 256
#define UB 8
#define TT (NB1 * NT1)           // 655,360 threads

__device__ __forceinline__ float s_from_w(float w) {   // fast, scan-only
    return sqrtf(__builtin_amdgcn_rcpf(w));
}
__device__ __forceinline__ float sigm_p(float x) {     // precise, matches ref
    return 1.0f / (1.0f + expf(-x));
}
__device__ __forceinline__ int bin_of(float s) {
    int b = (int)((s - HIST_LO) * HIST_SCALE);
    return b < 0 ? 0 : (b > HB - 1 ? HB - 1 : b);
}

// ------ Pass 1: batched-load scan; last block picks threshold bin T -----------
__global__ __launch_bounds__(NT1) void k_scan(
    const float* __restrict__ cls, const float* __restrict__ cent,
    unsigned* __restrict__ hist, unsigned* __restrict__ hdr,
    float* __restrict__ cscore, unsigned* __restrict__ cidx, int cap)
{
    __shared__ unsigned sh[HB];
    __shared__ float    sbs[SBUF];
    __shared__ unsigned sbi[SBUF];
    __shared__ unsigned sbn, sbase, sbm;
    __shared__ int      lastblk;
    for (int i = threadIdx.x; i < HB; i += NT1) sh[i] = 0;
    if (threadIdx.x == 0) sbn = 0;
    __syncthreads();

    const float4* c4 = (const float4*)cls;
    int tid = blockIdx.x * NT1 + threadIdx.x;

    // issue ALL 16 loads, then fence: loads cannot cross the memory clobber,
    // so none can be sunk into the consume loop (the round-4 regression).
    float  cb[UB];
    float4 v[UB];
    #pragma unroll
    for (int u = 0; u < UB; ++u) cb[u] = cent[(tid + u * TT) / 20];
    #pragma unroll
    for (int u = 0; u < UB; ++u) v[u] = c4[tid + u * TT];
    asm volatile("" ::: "memory");

    #pragma unroll
    for (int u = 0; u < UB; ++u) {
        int g = tid + u * TT;
        float f = 1.0f + __expf(-cb[u]);      // (1+e^-b), same point for all 4
        float sv[4] = {v[u].x, v[u].y, v[u].z, v[u].w};
        #pragma unroll
        for (int i = 0; i < 4; ++i) {
            float w = (1.0f + __expf(-sv[i])) * f;
            if (w <= W_HIST) {                // fast-s >= 0.90 (~0.06% of elems)
                float s = s_from_w(w);
                atomicAdd(&sh[bin_of(s)], 1u);
                if (w <= W_CAND) {            // fast-s >= 0.94 (~600 total)
                    unsigned gi = (unsigned)(g * 4 + i);
                    unsigned pos = atomicAdd(&sbn, 1u);
                    if (pos < SBUF) { sbs[pos] = s; sbi[pos] = gi; }
                    else {
                        unsigned q = atomicAdd(&hdr[0], 1u);
                        if (q < (unsigned)cap) { cscore[q] = s; cidx[q] = gi; }
                    }
                }
            }
        }
    }
    __syncthreads();
    // merge histogram (skip zero bins) + flush staging (1 counter atomic/block)
    for (int i = threadIdx.x; i < HB; i += NT1) {
        unsigned c = sh[i];
        if (c) atomicAdd(&hist[i], c);
    }
    if (threadIdx.x == 0) {
        unsigned m = sbn < SBUF ? sbn : SBUF;
        sbm = m;
        sbase = m ? atomicAdd(&hdr[0], m) : 0u;
    }
    __syncthreads();
    for (unsigned i = threadIdx.x; i < sbm; i += NT1) {
        unsigned q = sbase + i;
        if (q < (unsigned)cap) { cscore[q] = sbs[i]; cidx[q] = sbi[i]; }
    }
    __syncthreads();
    if (threadIdx.x == 0) {
        __threadfence();
        lastblk = (atomicAdd(&hdr[3], 1u) == (unsigned)(gridDim.x - 1));
    }
    __syncthreads();
    if (!lastblk) return;
    __threadfence();
    for (int i = threadIdx.x; i < HB; i += NT1)
        sh[i] = __hip_atomic_load(&hist[i], __ATOMIC_RELAXED, __HIP_MEMORY_SCOPE_AGENT);
    __syncthreads();
    if (threadIdx.x == 0) {
        unsigned cum = 0; int T = -1;
        for (int b = HB - 1; b >= 0; --b) { cum += sh[b]; if (cum >= KDET) { T = b; break; } }
        unsigned cand = __hip_atomic_load(&hdr[0], __ATOMIC_RELAXED, __HIP_MEMORY_SCOPE_AGENT);
        int rescan;
        if (T < 0) { T = 0; rescan = 1; }           // <100 fast-s >= 0.90 (never here)
        else {
            // finalize filters bins >= T-1; those must lie above theta0 + eps
            float edgeTm1 = HIST_LO + (float)(T - 1) * BINW;
            rescan = (edgeTm1 < THETA0 + 2.0f * BINW) || (cand > (unsigned)cap);
        }
        ((int*)hdr)[2] = T;
        __threadfence();
        hdr[1] = (unsigned)rescan;
    }
}

// ------ Pass 2: precise top-100, gather/decode, sort, NMS, outputs ------------
// (includes single-block rescan fallback; executes only on pathological inputs)
__global__ __launch_bounds__(256) void k_finalize(
    const float* __restrict__ cls, const float* __restrict__ cent,
    const float* __restrict__ boxp, const float* __restrict__ pts,
    const float* __restrict__ strd,
    const unsigned* __restrict__ hdr, const float* __restrict__ cscore,
    const unsigned* __restrict__ cidx, int cap, float* __restrict__ out)
{
    __shared__ float    ss[MCAP];
    __shared__ unsigned si[MCAP];
    __shared__ float    ps[MCAP];
    __shared__ unsigned mcnt;
    __shared__ float    tks[KDET];
    __shared__ unsigned tkj[KDET];
    __shared__ float sel_s[KDET];
    __shared__ int   sel_c[KDET];
    __shared__ float sel_b[KDET][4];
    __shared__ int   ordv[KDET];
    __shared__ float bs[KDET][4];
    __shared__ float sso[KDET];
    __shared__ int   cso[KDET];
    __shared__ unsigned char keepA[KDET];
    __shared__ float ioum[KDET * KDET];

    int T = ((const int*)hdr)[2];
    int Tm = T > 0 ? T - 1 : 0;
    if (threadIdx.x == 0) mcnt = 0;
    __syncthreads();

    if (hdr[1]) {
        // fallback: full rescan with this single block (correctness net only)
        const float4* c4 = (const float4*)cls;
        for (int g = threadIdx.x; g < NF4; g += 256) {
            float4 vv = c4[g];
            float f = 1.0f + __expf(-cent[g / 20]);
            float sv[4] = {vv.x, vv.y, vv.z, vv.w};
            #pragma unroll
            for (int i = 0; i < 4; ++i) {
                float w = (1.0f + __expf(-sv[i])) * f;
                if (w <= W_HIST) {
                    float s = s_from_w(w);
                    if (bin_of(s) >= Tm) {
                        unsigned p = atomicAdd(&mcnt, 1u);
                        if (p < MCAP) { ss[p] = s; si[p] = (unsigned)(g * 4 + i); }
                    }
                }
            }
        }
    } else {
        // filter stored candidates to bin >= T-1 (expected ~150)
        unsigned n = hdr[0]; if (n > (unsigned)cap) n = (unsigned)cap;
        for (unsigned i = threadIdx.x; i < n; i += 256) {
            float s = cscore[i];
            if (bin_of(s) >= Tm) {
                unsigned p = atomicAdd(&mcnt, 1u);
                if (p < MCAP) { ss[p] = s; si[p] = cidx[i]; }
            }
        }
    }
    __syncthreads();
    unsigned M = mcnt < MCAP ? mcnt : MCAP;

    // precise score per candidate (bit-identical to reference formula)
    for (unsigned m = threadIdx.x; m < M; m += 256) {
        unsigned j = si[m];
        ps[m] = sqrtf(sigm_p(cls[j]) * sigm_p(cent[j / (unsigned)NCLS]));
    }
    if (threadIdx.x < KDET) { tks[threadIdx.x] = -1.0f; tkj[threadIdx.x] = 0u; }
    __syncthreads();

    // exact top-100 by (precise score desc, idx asc) via rank counting
    for (unsigned m = threadIdx.x; m < M; m += 256) {
        float sm = ps[m]; unsigned jm = si[m];
        int rank = 0;
        for (unsigned q = 0; q < M; ++q) {
            float sq = ps[q]; unsigned jq = si[q];
            if (sq > sm || (sq == sm && jq < jm)) ++rank;
        }
        if (rank < KDET) { tks[rank] = sm; tkj[rank] = jm; }
    }
    __syncthreads();

    // gather + decode (faithful quirk: score gathered at flat[pt_idx])
    if (threadIdx.x < KDET) {
        int k = threadIdx.x;
        unsigned j = tkj[k];
        unsigned pt = j / (unsigned)NCLS;
        sel_c[k] = (int)(j % (unsigned)NCLS);
        sel_s[k] = sqrtf(sigm_p(cls[pt]) * sigm_p(cent[pt / (unsigned)NCLS]));
        float l = boxp[pt * 4 + 0], tt = boxp[pt * 4 + 1];
        float r = boxp[pt * 4 + 2], bb = boxp[pt * 4 + 3];
        float st = strd[pt];
        float px = pts[pt * 2 + 0], py = pts[pt * 2 + 1];
        sel_b[k][0] = __fsub_rn(px, __fmul_rn(l,  st));
        sel_b[k][1] = __fsub_rn(py, __fmul_rn(tt, st));
        sel_b[k][2] = __fadd_rn(px, __fmul_rn(r,  st));
        sel_b[k][3] = __fadd_rn(py, __fmul_rn(bb, st));
    }
    __syncthreads();

    // stable argsort(-sel_s): ties -> lower k (jnp.argsort stable)
    if (threadIdx.x < KDET) {
        int k = threadIdx.x; float sk = sel_s[k]; int rank = 0;
        for (int j = 0; j < KDET; ++j) {
            float sj = sel_s[j];
            if (sj > sk || (sj == sk && j < k)) ++rank;
        }
        ordv[rank] = k;
    }
    __syncthreads();
    if (threadIdx.x < KDET) {
        int i = threadIdx.x, o = ordv[i];
        sso[i] = sel_s[o]; cso[i] = sel_c[o];
        bs[i][0] = sel_b[o][0]; bs[i][1] = sel_b[o][1];
        bs[i][2] = sel_b[o][2]; bs[i][3] = sel_b[o][3];
        keepA[i] = 1;
    }
    __syncthreads();

    // pairwise IoU (exact reference formula)
    for (int t = threadIdx.x; t < KDET * KDET; t += 256) {
        int i = t / KDET, j = t % KDET;
        float ax1 = bs[i][0], ay1 = bs[i][1], ax2 = bs[i][2], ay2 = bs[i][3];
        float bx1 = bs[j][0], by1 = bs[j][1], bx2 = bs[j][2], by2 = bs[j][3];
        float areaA = (ax2 - ax1) * (ay2 - ay1);
        float areaB = (bx2 - bx1) * (by2 - by1);
        float lx = fmaxf(ax1, bx1), ly = fmaxf(ay1, by1);
        float rx = fminf(ax2, bx2), ry = fminf(ay2, by2);
        float w = fmaxf(rx - lx, 0.0f), h = fmaxf(ry - ly, 0.0f);
        float inter = w * h;
        ioum[t] = inter / (areaA + areaB - inter + 1e-9f);
    }
    __syncthreads();

    // greedy NMS on wave 0: keep flags in lane registers, zero barriers
    if (threadIdx.x < 64) {
        int L = threadIdx.x;
        int k0 = 1, k1 = 1;                  // boxes L and L+64
        #pragma unroll 1
        for (int i = 0; i < KDET; ++i) {
            int owner = (i < 64) ? i : (i - 64);
            int flag  = (i < 64) ? k0 : k1;
            int keep_i = __shfl(flag, owner, 64);
            if (keep_i) {
                if (L > i && ioum[i * KDET + L] > 0.5f) k0 = 0;
                int j2 = L + 64;
                if (j2 > i && j2 < KDET && ioum[i * KDET + j2] > 0.5f) k1 = 0;
            }
        }
        keepA[L] = (unsigned char)k0;
        if (L + 64 < KDET) keepA[L + 64] = (unsigned char)k1;
    }
    __syncthreads();

    // outputs: boxes [100,4] | scores [100] | classes [100] (float, -1 suppressed)
    if (threadIdx.x < KDET) {
        int i = threadIdx.x;
        bool kp = keepA[i] != 0;
        out[i * 4 + 0] = kp ? bs[i][0] : 0.0f;
        out[i * 4 + 1] = kp ? bs[i][1] : 0.0f;
        out[i * 4 + 2] = kp ? bs[i][2] : 0.0f;
        out[i * 4 + 3] = kp ? bs[i][3] : 0.0f;
        out[4 * KDET + i] = kp ? sso[i] : 0.0f;
        out[5 * KDET + i] = kp ? (float)cso[i] : -1.0f;
    }
}

extern "C" void kernel_launch(void* const* d_in, const int* in_sizes, int n_in,
                              void* d_out, int out_size, void* d_ws, size_t ws_size,
                              hipStream_t stream)
{
    const float* cls  = (const float*)d_in[0];
    const float* boxp = (const float*)d_in[1];
    const float* cent = (const float*)d_in[2];
    const float* pts  = (const float*)d_in[3];
    const float* strd = (const float*)d_in[4];
    float* out = (float*)d_out;

    char* ws = (char*)d_ws;
    unsigned* hdr  = (unsigned*)ws;
    unsigned* hist = (unsigned*)(ws + 16);
    size_t capS = ws_size > 2056 ? (ws_size - 2048) / 8 : 64;
    int cap = (int)(capS > 32768 ? 32768 : capS);
    float*    cscore = (float*)(ws + 2048);
    unsigned* cidx   = (unsigned*)(ws + 2048 + (size_t)cap * 4);

    hipMemsetAsync(d_ws, 0, 2048, stream);  // header + hist
    hipLaunchKernelGGL(k_scan, dim3(NB1), dim3(NT1), 0, stream,
                       cls, cent, hist, hdr, cscore, cidx, cap);
    hipLaunchKernelGGL(k_finalize, dim3(1), dim3(256), 0, stream,
                       cls, cent, boxp, pts, strd, hdr, cscore, cidx, cap, out);
}